// Round 1
// 2559.160 us; speedup vs baseline: 1.6415x; 1.6415x over previous
//
#include <hip/hip_runtime.h>

#define N_NODES 50000
#define N_EDGES 400000
#define DIM 512
#define N_LAYERS 4
#define N_GRAPHS 500
#define EPS_F 1e-5f
#define NEG 0.01f
#define MP 50048   // 391 * 128, padded row count for GEMM tiles

typedef __attribute__((ext_vector_type(8))) short short8v;  // 8 bf16 (4 VGPRs)
typedef __attribute__((ext_vector_type(4))) float f32x4;

__device__ __forceinline__ float leaky(float x) { return x >= 0.f ? x : NEG * x; }

// fp32 -> bf16 bits, round-to-nearest-even
__device__ __forceinline__ unsigned f2bf(float f) {
    unsigned u = __float_as_uint(f);
    return (u + 0x7FFFu + ((u >> 16) & 1u)) >> 16;
}
__device__ __forceinline__ float bf2f(unsigned h) { return __uint_as_float(h << 16); }

__device__ __forceinline__ void gll16(const void* g, void* l) {
    __builtin_amdgcn_global_load_lds(
        (__attribute__((address_space(1))) void*)(void*)g,
        (__attribute__((address_space(3))) void*)l, 16, 0, 0);
}

// ---------------- CSR build: histogram of dst ----------------
__global__ __launch_bounds__(256) void hist_k(const int* __restrict__ ei, int* __restrict__ deg)
{
    int e = blockIdx.x * 256 + threadIdx.x;
    if (e < N_EDGES) atomicAdd(&deg[ei[N_EDGES + e]], 1);
}

// ---------------- CSR build: exclusive scan (single block) ----------------
__global__ __launch_bounds__(1024) void scan_k(const int* __restrict__ deg,
                                               int* __restrict__ off, int* __restrict__ cursor)
{
    __shared__ int sums[1024];
    const int t = threadIdx.x;
    const int CH = (N_NODES + 1023) / 1024;   // 49
    const int base = t * CH;
    int s = 0;
    for (int i = 0; i < CH; ++i) {
        int idx = base + i;
        if (idx < N_NODES) s += deg[idx];
    }
    sums[t] = s;
    __syncthreads();
    for (int d = 1; d < 1024; d <<= 1) {
        int v = 0;
        if (t >= d) v = sums[t - d];
        __syncthreads();
        if (t >= d) sums[t] += v;
        __syncthreads();
    }
    int run = (t == 0) ? 0 : sums[t - 1];
    for (int i = 0; i < CH; ++i) {
        int idx = base + i;
        if (idx < N_NODES) {
            off[idx] = run;
            cursor[idx] = run;
            run += deg[idx];
        }
    }
    if (t == 1023) off[N_NODES] = sums[1023];
}

// ---------------- CSR build: fill src lists ----------------
__global__ __launch_bounds__(256) void fill_k(const int* __restrict__ ei,
                                              int* __restrict__ cursor, int* __restrict__ csr)
{
    int e = blockIdx.x * 256 + threadIdx.x;
    if (e < N_EDGES) {
        int dst = ei[N_EDGES + e];
        int p = atomicAdd(&cursor[dst], 1);
        csr[p] = ei[e];
    }
}

// --------- weight prep: transpose W[k][n] -> Wt[n][k], split hi/lo bf16 ---------
// grid (16,16,8): x = n-tile, y = k-tile, z = matrix (0..3 = W1 layers, 4..7 = W2 layers)
__global__ __launch_bounds__(256) void wprep_k(
    const float* __restrict__ W1, const float* __restrict__ W2,
    ushort* __restrict__ Bh, ushort* __restrict__ Bl)
{
    __shared__ float t[32][33];
    int m = blockIdx.z;
    const float* W = (m < N_LAYERS) ? (W1 + (size_t)m * DIM * DIM)
                                    : (W2 + (size_t)(m - N_LAYERS) * DIM * DIM);
    int n0 = blockIdx.x * 32, k0 = blockIdx.y * 32;
    int tx = threadIdx.x, ty = threadIdx.y;   // 32 x 8
    for (int r = ty; r < 32; r += 8)
        t[r][tx] = W[(size_t)(k0 + r) * DIM + n0 + tx];
    __syncthreads();
    size_t ob = (size_t)m * DIM * DIM;
    for (int r = ty; r < 32; r += 8) {
        float v = t[tx][r];                   // = W[k0+tx][n0+r]
        unsigned hh = f2bf(v);
        unsigned ll = f2bf(v - bf2f(hh));
        Bh[ob + (size_t)(n0 + r) * DIM + k0 + tx] = (ushort)hh;
        Bl[ob + (size_t)(n0 + r) * DIM + k0 + tx] = (ushort)ll;
    }
}

// ---- gather aggregation: z[n] = h[n] + sum_{e: dst=n} h[src]; write bf16 hi/lo pair ----
__global__ __launch_bounds__(256) void aggregate_k(
    const int* __restrict__ off, const int* __restrict__ csr,
    const float* __restrict__ h, int hstride,
    ushort* __restrict__ Ah, ushort* __restrict__ Al)
{
    int n = blockIdx.x * 4 + (threadIdx.x >> 6);
    if (n >= N_NODES) return;
    int lane = threadIdx.x & 63;
    int c = lane * 8;

    const float* hp = h + (size_t)n * hstride + c;
    float acc[8];
    *(float4*)&acc[0] = *(const float4*)hp;
    *(float4*)&acc[4] = *(const float4*)(hp + 4);

    int e0 = off[n], e1 = off[n + 1];
    for (int e = e0; e < e1; ++e) {
        int src = csr[e];
        const float* sp = h + (size_t)src * hstride + c;
        float4 a = *(const float4*)sp;
        float4 b = *(const float4*)(sp + 4);
        acc[0] += a.x; acc[1] += a.y; acc[2] += a.z; acc[3] += a.w;
        acc[4] += b.x; acc[5] += b.y; acc[6] += b.z; acc[7] += b.w;
    }
    unsigned hb[8], lb[8];
#pragma unroll
    for (int i = 0; i < 8; ++i) {
        hb[i] = f2bf(acc[i]);
        lb[i] = f2bf(acc[i] - bf2f(hb[i]));
    }
    uint4 H = make_uint4(hb[0] | (hb[1] << 16), hb[2] | (hb[3] << 16),
                         hb[4] | (hb[5] << 16), hb[6] | (hb[7] << 16));
    uint4 L = make_uint4(lb[0] | (lb[1] << 16), lb[2] | (lb[3] << 16),
                         lb[4] | (lb[5] << 16), lb[6] | (lb[7] << 16));
    *(uint4*)(Ah + (size_t)n * DIM + c) = H;
    *(uint4*)(Al + (size_t)n * DIM + c) = L;
}

// ---------------- split-precision MFMA GEMM ----------------
// C = leaky(A @ B + bias),  A fp32 ~= Ah + Al (bf16 pair, [MP][512] k-contig),
// B given transposed+split: Bt[n][k] pairs.  C = Ah*Bh + Ah*Bl + Al*Bh (fp32 acc).
// 128x128 tile, BK=32, 256 thr = 4 waves, each wave a 64x64 sub-tile (4x4 frags of 16x16x32).
// LDS rows are 64B (4 x 16B chunks); chunk swizzle c ^= ((row>>1)&3) applied via
// pre-swizzled global source (global_load_lds dest must stay linear).
template<int OUTBF>
__global__ __launch_bounds__(256) void gemm_mfma_k(
    const ushort* __restrict__ Ah, const ushort* __restrict__ Al,
    const ushort* __restrict__ Bh, const ushort* __restrict__ Bl,
    const float* __restrict__ bias,
    float* __restrict__ Cf, ushort* __restrict__ Ch, ushort* __restrict__ Cl,
    int M)
{
    __shared__ __align__(16) ushort lds[4][128 * 32];   // Ah,Al,Bh,Bl tiles: 8 KB each
    const int tid = threadIdx.x;
    const int wave = tid >> 6, lane = tid & 63;
    const int row0 = blockIdx.y * 128;
    const int col0 = blockIdx.x * 128;

    // ---- staging addressing: lane -> (row, chunk) of a 16-row / 1KB wave-load ----
    const int rl = lane >> 2;        // 0..15
    const int cch = lane & 3;        // chunk slot in LDS (linear dest)
    const int r0 = wave * 16 + rl;   // rows 0..63   (L=0)
    const int r1 = r0 + 64;          // rows 64..127 (L=1)
    const int kc0 = (cch ^ ((r0 >> 1) & 3)) * 8;  // pre-swizzled source k-chunk (ushorts)
    const int kc1 = (cch ^ ((r1 >> 1) & 3)) * 8;

    const ushort* sAh0 = Ah + (size_t)(row0 + r0) * DIM + kc0;
    const ushort* sAh1 = Ah + (size_t)(row0 + r1) * DIM + kc1;
    const ushort* sAl0 = Al + (size_t)(row0 + r0) * DIM + kc0;
    const ushort* sAl1 = Al + (size_t)(row0 + r1) * DIM + kc1;
    const ushort* sBh0 = Bh + (size_t)(col0 + r0) * DIM + kc0;
    const ushort* sBh1 = Bh + (size_t)(col0 + r1) * DIM + kc1;
    const ushort* sBl0 = Bl + (size_t)(col0 + r0) * DIM + kc0;
    const ushort* sBl1 = Bl + (size_t)(col0 + r1) * DIM + kc1;

    ushort* dAh0 = &lds[0][(wave * 16) * 32];
    ushort* dAh1 = &lds[0][(wave * 16 + 64) * 32];
    ushort* dAl0 = &lds[1][(wave * 16) * 32];
    ushort* dAl1 = &lds[1][(wave * 16 + 64) * 32];
    ushort* dBh0 = &lds[2][(wave * 16) * 32];
    ushort* dBh1 = &lds[2][(wave * 16 + 64) * 32];
    ushort* dBl0 = &lds[3][(wave * 16) * 32];
    ushort* dBl1 = &lds[3][(wave * 16 + 64) * 32];

    // ---- fragment read offsets (k-invariant, swizzled) ----
    const int lr = lane & 15, kb = lane >> 4;
    int aoffB[4], boffB[4];
#pragma unroll
    for (int f = 0; f < 4; ++f) {
        int ra = (wave >> 1) * 64 + f * 16 + lr;
        aoffB[f] = ra * 64 + ((kb ^ ((ra >> 1) & 3)) * 16);
        int rb = (wave & 1) * 64 + f * 16 + lr;
        boffB[f] = rb * 64 + ((kb ^ ((rb >> 1) & 3)) * 16);
    }
    const char* base = (const char*)&lds[0][0];  // tiles at +0, +8192, +16384, +24576

    f32x4 acc[4][4];
#pragma unroll
    for (int i = 0; i < 4; ++i)
#pragma unroll
        for (int j = 0; j < 4; ++j) acc[i][j] = (f32x4)0.f;

    for (int ks = 0; ks < DIM / 32; ++ks) {
        gll16(sAh0, dAh0); gll16(sAh1, dAh1);
        gll16(sAl0, dAl0); gll16(sAl1, dAl1);
        gll16(sBh0, dBh0); gll16(sBh1, dBh1);
        gll16(sBl0, dBl0); gll16(sBl1, dBl1);
        sAh0 += 32; sAh1 += 32; sAl0 += 32; sAl1 += 32;
        sBh0 += 32; sBh1 += 32; sBl0 += 32; sBl1 += 32;
        __syncthreads();   // drains vmcnt: staged data visible

        short8v ah[4], al[4], bh[4], bl[4];
#pragma unroll
        for (int f = 0; f < 4; ++f) {
            ah[f] = *(const short8v*)(base +         aoffB[f]);
            al[f] = *(const short8v*)(base +  8192 + aoffB[f]);
            bh[f] = *(const short8v*)(base + 16384 + boffB[f]);
            bl[f] = *(const short8v*)(base + 24576 + boffB[f]);
        }
#pragma unroll
        for (int i = 0; i < 4; ++i)
#pragma unroll
            for (int j = 0; j < 4; ++j) {
                acc[i][j] = __builtin_amdgcn_mfma_f32_16x16x32_bf16(ah[i], bh[j], acc[i][j], 0, 0, 0);
                acc[i][j] = __builtin_amdgcn_mfma_f32_16x16x32_bf16(ah[i], bl[j], acc[i][j], 0, 0, 0);
                acc[i][j] = __builtin_amdgcn_mfma_f32_16x16x32_bf16(al[i], bh[j], acc[i][j], 0, 0, 0);
            }
        __syncthreads();   // protect LDS from next iteration's staging
    }

    // ---- epilogue: C/D layout col = lane&15, row = (lane>>4)*4 + reg ----
    const int colB = col0 + (wave & 1) * 64 + lr;
    const int rowB = row0 + (wave >> 1) * 64 + kb * 4;
    float bv[4];
#pragma unroll
    for (int j = 0; j < 4; ++j) bv[j] = bias[colB + j * 16];
#pragma unroll
    for (int i = 0; i < 4; ++i) {
#pragma unroll
        for (int j = 0; j < 4; ++j) {
            int cg = colB + j * 16;
#pragma unroll
            for (int rg = 0; rg < 4; ++rg) {
                int rr = rowB + i * 16 + rg;
                if (rr < M) {
                    float o = leaky(acc[i][j][rg] + bv[j]);
                    if (OUTBF) {
                        unsigned hh = f2bf(o);
                        Ch[(size_t)rr * DIM + cg] = (ushort)hh;
                        Cl[(size_t)rr * DIM + cg] = (ushort)f2bf(o - bf2f(hh));
                    } else {
                        Cf[(size_t)rr * DIM + cg] = o;
                    }
                }
            }
        }
    }
}

// ------- NodeNorm (in place) + per-block BatchNorm partial stats -------
__global__ __launch_bounds__(256) void nodenorm_k(
    float* __restrict__ z, float* __restrict__ partials)
{
    __shared__ float part[1024];
    for (int t = threadIdx.x; t < 1024; t += 256) part[t] = 0.f;
    __syncthreads();

    int wave = blockIdx.x * 4 + (threadIdx.x >> 6);
    int lane = threadIdx.x & 63;
    int nw = gridDim.x * 4;
    int per = (N_NODES + nw - 1) / nw;
    int r0 = wave * per;
    int r1 = min(N_NODES, r0 + per);

    float cs[8] = {0, 0, 0, 0, 0, 0, 0, 0};
    float cq[8] = {0, 0, 0, 0, 0, 0, 0, 0};

    for (int r = r0; r < r1; ++r) {
        float* p = z + (size_t)r * DIM;
        float4 a = *(const float4*)(p + lane * 4);
        float4 b = *(const float4*)(p + 256 + lane * 4);
        float s = a.x + a.y + a.z + a.w + b.x + b.y + b.z + b.w;
        float q = a.x * a.x + a.y * a.y + a.z * a.z + a.w * a.w
                + b.x * b.x + b.y * b.y + b.z * b.z + b.w * b.w;
#pragma unroll
        for (int off = 32; off; off >>= 1) {
            s += __shfl_xor(s, off);
            q += __shfl_xor(q, off);
        }
        float mean = s * (1.f / DIM);
        float var = q * (1.f / DIM) - mean * mean;
        float rs = rsqrtf(var + EPS_F);
        a.x = (a.x - mean) * rs; a.y = (a.y - mean) * rs;
        a.z = (a.z - mean) * rs; a.w = (a.w - mean) * rs;
        b.x = (b.x - mean) * rs; b.y = (b.y - mean) * rs;
        b.z = (b.z - mean) * rs; b.w = (b.w - mean) * rs;
        *(float4*)(p + lane * 4) = a;
        *(float4*)(p + 256 + lane * 4) = b;
        cs[0] += a.x; cs[1] += a.y; cs[2] += a.z; cs[3] += a.w;
        cs[4] += b.x; cs[5] += b.y; cs[6] += b.z; cs[7] += b.w;
        cq[0] += a.x * a.x; cq[1] += a.y * a.y; cq[2] += a.z * a.z; cq[3] += a.w * a.w;
        cq[4] += b.x * b.x; cq[5] += b.y * b.y; cq[6] += b.z * b.z; cq[7] += b.w * b.w;
    }
#pragma unroll
    for (int i = 0; i < 4; ++i) {
        atomicAdd(&part[lane * 4 + i], cs[i]);
        atomicAdd(&part[256 + lane * 4 + i], cs[4 + i]);
        atomicAdd(&part[512 + lane * 4 + i], cq[i]);
        atomicAdd(&part[768 + lane * 4 + i], cq[4 + i]);
    }
    __syncthreads();
    float* dst = partials + (size_t)blockIdx.x * 1024;
    *(float4*)(dst + threadIdx.x * 4) = *(const float4*)&part[threadIdx.x * 4];
}

// ------- BatchNorm finalize: scale/shift per column -------
__global__ void bn_finalize_k(
    const float* __restrict__ partials, int nblocks,
    const float* __restrict__ gamma, const float* __restrict__ beta,
    float* __restrict__ sc, float* __restrict__ sh)
{
    int c = blockIdx.x * blockDim.x + threadIdx.x;
    if (c >= DIM) return;
    float s = 0.f, q = 0.f;
#pragma unroll 8
    for (int b = 0; b < nblocks; ++b) {
        s += partials[(size_t)b * 1024 + c];
        q += partials[(size_t)b * 1024 + 512 + c];
    }
    float mean = s * (1.f / N_NODES);
    float var = q * (1.f / N_NODES) - mean * mean;
    float sf = gamma[c] * rsqrtf(var + EPS_F);
    sc[c] = sf;
    sh[c] = beta[c] - mean * sf;
}

// ------- BatchNorm apply + x_local write + sorted-segment pooling -------
__global__ __launch_bounds__(256) void apply_pool_k(
    const float* __restrict__ z, const float* __restrict__ sc, const float* __restrict__ sh,
    const int* __restrict__ batch,
    float* __restrict__ xloc, float* __restrict__ xglob)
{
    int wave = blockIdx.x * 4 + (threadIdx.x >> 6);
    int lane = threadIdx.x & 63;
    int nw = gridDim.x * 4;
    int per = (N_NODES + nw - 1) / nw;
    int r0 = wave * per;
    int r1 = min(N_NODES, r0 + per);
    if (r0 >= r1) return;

    float4 s0 = *(const float4*)(sc + lane * 4);
    float4 s1 = *(const float4*)(sc + 256 + lane * 4);
    float4 t0 = *(const float4*)(sh + lane * 4);
    float4 t1 = *(const float4*)(sh + 256 + lane * 4);

    float pa[8] = {0, 0, 0, 0, 0, 0, 0, 0};
    int curg = batch[r0];
    const int LD = N_LAYERS * DIM;

    for (int r = r0; r < r1; ++r) {
        int g = batch[r];
        if (g != curg) {
#pragma unroll
            for (int i = 0; i < 4; ++i) {
                atomicAdd(xglob + (size_t)curg * LD + lane * 4 + i, pa[i]);
                atomicAdd(xglob + (size_t)curg * LD + 256 + lane * 4 + i, pa[4 + i]);
                pa[i] = 0.f; pa[4 + i] = 0.f;
            }
            curg = g;
        }
        const float* p = z + (size_t)r * DIM;
        float4 a = *(const float4*)(p + lane * 4);
        float4 b = *(const float4*)(p + 256 + lane * 4);
        a.x = fmaf(a.x, s0.x, t0.x); a.y = fmaf(a.y, s0.y, t0.y);
        a.z = fmaf(a.z, s0.z, t0.z); a.w = fmaf(a.w, s0.w, t0.w);
        b.x = fmaf(b.x, s1.x, t1.x); b.y = fmaf(b.y, s1.y, t1.y);
        b.z = fmaf(b.z, s1.z, t1.z); b.w = fmaf(b.w, s1.w, t1.w);
        *(float4*)(xloc + (size_t)r * LD + lane * 4) = a;
        *(float4*)(xloc + (size_t)r * LD + 256 + lane * 4) = b;
        pa[0] += a.x; pa[1] += a.y; pa[2] += a.z; pa[3] += a.w;
        pa[4] += b.x; pa[5] += b.y; pa[6] += b.z; pa[7] += b.w;
    }
#pragma unroll
    for (int i = 0; i < 4; ++i) {
        atomicAdd(xglob + (size_t)curg * LD + lane * 4 + i, pa[i]);
        atomicAdd(xglob + (size_t)curg * LD + 256 + lane * 4 + i, pa[4 + i]);
    }
}

extern "C" void kernel_launch(void* const* d_in, const int* in_sizes, int n_in,
                              void* d_out, int out_size, void* d_ws, size_t ws_size,
                              hipStream_t stream)
{
    const float* x     = (const float*)d_in[0];
    const int*   ei    = (const int*)d_in[1];
    const int*   batch = (const int*)d_in[2];
    const float* W1    = (const float*)d_in[3];
    const float* b1    = (const float*)d_in[4];
    const float* W2    = (const float*)d_in[5];
    const float* b2    = (const float*)d_in[6];
    const float* gamma = (const float*)d_in[7];
    const float* beta  = (const float*)d_in[8];

    float* out = (float*)d_out;
    const size_t XG = (size_t)N_GRAPHS * N_LAYERS * DIM;
    float* xglob_base = out;
    float* xloc_base  = out + XG;

    const size_t PAIR_ELEMS = (size_t)MP * DIM;   // ushorts per hi or lo matrix
    char* w = (char*)d_ws;
    ushort* Ah0 = (ushort*)w;
    ushort* Al0 = Ah0 + PAIR_ELEMS;
    float*  fbuf = (float*)w;                     // aliases Ah0/Al0 — lifetimes disjoint
    w += PAIR_ELEMS * 2 * sizeof(ushort);
    ushort* Ah1 = (ushort*)w;
    ushort* Al1 = Ah1 + PAIR_ELEMS;
    w += PAIR_ELEMS * 2 * sizeof(ushort);
    ushort* Wh = (ushort*)w; w += (size_t)2 * N_LAYERS * DIM * DIM * sizeof(ushort);
    ushort* Wl = (ushort*)w; w += (size_t)2 * N_LAYERS * DIM * DIM * sizeof(ushort);
    const int NN_BLOCKS = 256;
    float* partials = (float*)w; w += (size_t)NN_BLOCKS * 1024 * sizeof(float);
    float* sc = (float*)w; w += DIM * sizeof(float);
    float* sh = (float*)w; w += DIM * sizeof(float);
    int* deg    = (int*)w; w += (size_t)N_NODES * sizeof(int);
    int* off    = (int*)w; w += (size_t)(N_NODES + 1) * sizeof(int);
    int* cursor = (int*)w; w += (size_t)N_NODES * sizeof(int);
    int* csr    = (int*)w;

    hipMemsetAsync(xglob_base, 0, XG * sizeof(float), stream);
    hipMemsetAsync(deg, 0, N_NODES * sizeof(int), stream);

    // CSR build + weight prep (once per launch)
    hist_k<<<(N_EDGES + 255) / 256, 256, 0, stream>>>(ei, deg);
    scan_k<<<1, 1024, 0, stream>>>(deg, off, cursor);
    fill_k<<<(N_EDGES + 255) / 256, 256, 0, stream>>>(ei, cursor, csr);
    wprep_k<<<dim3(16, 16, 2 * N_LAYERS), dim3(32, 8), 0, stream>>>(W1, W2, Wh, Wl);

    for (int i = 0; i < N_LAYERS; ++i) {
        const float* h;
        int hstride;
        if (i == 0) { h = x; hstride = DIM; }
        else        { h = xloc_base + (size_t)(i - 1) * DIM; hstride = N_LAYERS * DIM; }

        aggregate_k<<<(N_NODES + 3) / 4, 256, 0, stream>>>(off, csr, h, hstride, Ah0, Al0);

        // GEMM1: z1 = leaky(z @ W1 + b1), output as bf16 hi/lo pair
        gemm_mfma_k<1><<<dim3(DIM / 128, (MP / 128)), 256, 0, stream>>>(
            Ah0, Al0,
            Wh + (size_t)i * DIM * DIM, Wl + (size_t)i * DIM * DIM,
            b1 + (size_t)i * DIM, nullptr, Ah1, Al1, N_NODES);

        // GEMM2: z2 = leaky(z1 @ W2 + b2), fp32 output for normalization
        gemm_mfma_k<0><<<dim3(DIM / 128, (MP / 128)), 256, 0, stream>>>(
            Ah1, Al1,
            Wh + (size_t)(N_LAYERS + i) * DIM * DIM, Wl + (size_t)(N_LAYERS + i) * DIM * DIM,
            b2 + (size_t)i * DIM, fbuf, nullptr, nullptr, N_NODES);

        nodenorm_k<<<NN_BLOCKS, 256, 0, stream>>>(fbuf, partials);

        bn_finalize_k<<<2, 256, 0, stream>>>(partials, NN_BLOCKS,
            gamma + (size_t)i * DIM, beta + (size_t)i * DIM, sc, sh);

        apply_pool_k<<<512, 256, 0, stream>>>(fbuf, sc, sh, batch,
            xloc_base + (size_t)i * DIM, xglob_base + (size_t)i * DIM);
    }
}

// Round 2
// 2551.375 us; speedup vs baseline: 1.6465x; 1.0031x over previous
//
#include <hip/hip_runtime.h>

#define N_NODES 50000
#define N_EDGES 400000
#define DIM 512
#define N_LAYERS 4
#define N_GRAPHS 500
#define EPS_F 1e-5f
#define NEG 0.01f
#define MP 50048   // 391 * 128, padded row count for GEMM tiles

typedef __attribute__((ext_vector_type(8))) short short8v;  // 8 bf16 (4 VGPRs)
typedef __attribute__((ext_vector_type(4))) float f32x4;

__device__ __forceinline__ float leaky(float x) { return x >= 0.f ? x : NEG * x; }

// fp32 -> bf16 bits, round-to-nearest-even
__device__ __forceinline__ unsigned f2bf(float f) {
    unsigned u = __float_as_uint(f);
    return (u + 0x7FFFu + ((u >> 16) & 1u)) >> 16;
}
__device__ __forceinline__ float bf2f(unsigned h) { return __uint_as_float(h << 16); }

__device__ __forceinline__ void gll16(const void* g, void* l) {
    __builtin_amdgcn_global_load_lds(
        (__attribute__((address_space(1))) void*)(void*)g,
        (__attribute__((address_space(3))) void*)l, 16, 0, 0);
}

// ---------------- CSR build: histogram of dst ----------------
__global__ __launch_bounds__(256) void hist_k(const int* __restrict__ ei, int* __restrict__ deg)
{
    int e = blockIdx.x * 256 + threadIdx.x;
    if (e < N_EDGES) atomicAdd(&deg[ei[N_EDGES + e]], 1);
}

// ---------------- CSR build: exclusive scan (single block) ----------------
__global__ __launch_bounds__(1024) void scan_k(const int* __restrict__ deg,
                                               int* __restrict__ off, int* __restrict__ cursor)
{
    __shared__ int sums[1024];
    const int t = threadIdx.x;
    const int CH = (N_NODES + 1023) / 1024;   // 49
    const int base = t * CH;
    int s = 0;
    for (int i = 0; i < CH; ++i) {
        int idx = base + i;
        if (idx < N_NODES) s += deg[idx];
    }
    sums[t] = s;
    __syncthreads();
    for (int d = 1; d < 1024; d <<= 1) {
        int v = 0;
        if (t >= d) v = sums[t - d];
        __syncthreads();
        if (t >= d) sums[t] += v;
        __syncthreads();
    }
    int run = (t == 0) ? 0 : sums[t - 1];
    for (int i = 0; i < CH; ++i) {
        int idx = base + i;
        if (idx < N_NODES) {
            off[idx] = run;
            cursor[idx] = run;
            run += deg[idx];
        }
    }
    if (t == 1023) off[N_NODES] = sums[1023];
}

// ---------------- CSR build: fill src lists ----------------
__global__ __launch_bounds__(256) void fill_k(const int* __restrict__ ei,
                                              int* __restrict__ cursor, int* __restrict__ csr)
{
    int e = blockIdx.x * 256 + threadIdx.x;
    if (e < N_EDGES) {
        int dst = ei[N_EDGES + e];
        int p = atomicAdd(&cursor[dst], 1);
        csr[p] = ei[e];
    }
}

// --------- weight prep: transpose W[k][n] -> Wt[n][k], split hi/lo bf16 ---------
__global__ __launch_bounds__(256) void wprep_k(
    const float* __restrict__ W1, const float* __restrict__ W2,
    ushort* __restrict__ Bh, ushort* __restrict__ Bl)
{
    __shared__ float t[32][33];
    int m = blockIdx.z;
    const float* W = (m < N_LAYERS) ? (W1 + (size_t)m * DIM * DIM)
                                    : (W2 + (size_t)(m - N_LAYERS) * DIM * DIM);
    int n0 = blockIdx.x * 32, k0 = blockIdx.y * 32;
    int tx = threadIdx.x, ty = threadIdx.y;   // 32 x 8
    for (int r = ty; r < 32; r += 8)
        t[r][tx] = W[(size_t)(k0 + r) * DIM + n0 + tx];
    __syncthreads();
    size_t ob = (size_t)m * DIM * DIM;
    for (int r = ty; r < 32; r += 8) {
        float v = t[tx][r];                   // = W[k0+tx][n0+r]
        unsigned hh = f2bf(v);
        unsigned ll = f2bf(v - bf2f(hh));
        Bh[ob + (size_t)(n0 + r) * DIM + k0 + tx] = (ushort)hh;
        Bl[ob + (size_t)(n0 + r) * DIM + k0 + tx] = (ushort)ll;
    }
}

// ---- gather aggregation: z[n] = h[n] + sum_{e: dst=n} h[src]; write bf16 hi/lo pair ----
// one wave per node; lane owns 8 consecutive floats. Edge loop unrolled x4 with all
// 8 float4 gathers issued before accumulation: ~128B/lane in flight (latency hiding).
__global__ __launch_bounds__(256) void aggregate_k(
    const int* __restrict__ off, const int* __restrict__ csr,
    const float* __restrict__ h, int hstride,
    ushort* __restrict__ Ah, ushort* __restrict__ Al)
{
    int n = blockIdx.x * 4 + (threadIdx.x >> 6);
    if (n >= N_NODES) return;
    int lane = threadIdx.x & 63;
    int c = lane * 8;

    const float* hp = h + (size_t)n * hstride + c;
    float acc[8], acc2[8];
    *(float4*)&acc[0] = *(const float4*)hp;
    *(float4*)&acc[4] = *(const float4*)(hp + 4);
#pragma unroll
    for (int j = 0; j < 8; ++j) acc2[j] = 0.f;

    int e0 = off[n], e1 = off[n + 1];
    int e = e0;
    for (; e + 4 <= e1; e += 4) {
        int s0 = csr[e], s1 = csr[e + 1], s2 = csr[e + 2], s3 = csr[e + 3];
        const float* p0 = h + (size_t)s0 * hstride + c;
        const float* p1 = h + (size_t)s1 * hstride + c;
        const float* p2 = h + (size_t)s2 * hstride + c;
        const float* p3 = h + (size_t)s3 * hstride + c;
        float v0[8], v1[8], v2[8], v3[8];
        *(float4*)&v0[0] = *(const float4*)p0;
        *(float4*)&v0[4] = *(const float4*)(p0 + 4);
        *(float4*)&v1[0] = *(const float4*)p1;
        *(float4*)&v1[4] = *(const float4*)(p1 + 4);
        *(float4*)&v2[0] = *(const float4*)p2;
        *(float4*)&v2[4] = *(const float4*)(p2 + 4);
        *(float4*)&v3[0] = *(const float4*)p3;
        *(float4*)&v3[4] = *(const float4*)(p3 + 4);
#pragma unroll
        for (int j = 0; j < 8; ++j) {
            acc[j]  += v0[j] + v1[j];
            acc2[j] += v2[j] + v3[j];
        }
    }
    for (; e < e1; ++e) {
        int src = csr[e];
        const float* sp = h + (size_t)src * hstride + c;
        float v[8];
        *(float4*)&v[0] = *(const float4*)sp;
        *(float4*)&v[4] = *(const float4*)(sp + 4);
#pragma unroll
        for (int j = 0; j < 8; ++j) acc[j] += v[j];
    }
#pragma unroll
    for (int j = 0; j < 8; ++j) acc[j] += acc2[j];

    unsigned hb[8], lb[8];
#pragma unroll
    for (int i = 0; i < 8; ++i) {
        hb[i] = f2bf(acc[i]);
        lb[i] = f2bf(acc[i] - bf2f(hb[i]));
    }
    uint4 H = make_uint4(hb[0] | (hb[1] << 16), hb[2] | (hb[3] << 16),
                         hb[4] | (hb[5] << 16), hb[6] | (hb[7] << 16));
    uint4 L = make_uint4(lb[0] | (lb[1] << 16), lb[2] | (lb[3] << 16),
                         lb[4] | (lb[5] << 16), lb[6] | (lb[7] << 16));
    *(uint4*)(Ah + (size_t)n * DIM + c) = H;
    *(uint4*)(Al + (size_t)n * DIM + c) = L;
}

// ---------------- split-precision MFMA GEMM ----------------
// C = leaky(A @ B + bias),  A fp32 ~= Ah + Al (bf16 pair, [MP][512] k-contig),
// B given transposed+split: Bt[n][k] pairs.  C = Ah*Bh + Ah*Bl + Al*Bh (fp32 acc).
// 128x128 tile, BK=32, 256 thr = 4 waves, each wave a 64x64 sub-tile (4x4 frags of 16x16x32).
template<int OUTBF>
__global__ __launch_bounds__(256) void gemm_mfma_k(
    const ushort* __restrict__ Ah, const ushort* __restrict__ Al,
    const ushort* __restrict__ Bh, const ushort* __restrict__ Bl,
    const float* __restrict__ bias,
    float* __restrict__ Cf, ushort* __restrict__ Ch, ushort* __restrict__ Cl,
    int M)
{
    __shared__ __align__(16) ushort lds[4][128 * 32];   // Ah,Al,Bh,Bl tiles: 8 KB each
    const int tid = threadIdx.x;
    const int wave = tid >> 6, lane = tid & 63;
    const int row0 = blockIdx.y * 128;
    const int col0 = blockIdx.x * 128;

    const int rl = lane >> 2;        // 0..15
    const int cch = lane & 3;        // chunk slot in LDS (linear dest)
    const int r0 = wave * 16 + rl;   // rows 0..63   (L=0)
    const int r1 = r0 + 64;          // rows 64..127 (L=1)
    const int kc0 = (cch ^ ((r0 >> 1) & 3)) * 8;  // pre-swizzled source k-chunk (ushorts)
    const int kc1 = (cch ^ ((r1 >> 1) & 3)) * 8;

    const ushort* sAh0 = Ah + (size_t)(row0 + r0) * DIM + kc0;
    const ushort* sAh1 = Ah + (size_t)(row0 + r1) * DIM + kc1;
    const ushort* sAl0 = Al + (size_t)(row0 + r0) * DIM + kc0;
    const ushort* sAl1 = Al + (size_t)(row0 + r1) * DIM + kc1;
    const ushort* sBh0 = Bh + (size_t)(col0 + r0) * DIM + kc0;
    const ushort* sBh1 = Bh + (size_t)(col0 + r1) * DIM + kc1;
    const ushort* sBl0 = Bl + (size_t)(col0 + r0) * DIM + kc0;
    const ushort* sBl1 = Bl + (size_t)(col0 + r1) * DIM + kc1;

    ushort* dAh0 = &lds[0][(wave * 16) * 32];
    ushort* dAh1 = &lds[0][(wave * 16 + 64) * 32];
    ushort* dAl0 = &lds[1][(wave * 16) * 32];
    ushort* dAl1 = &lds[1][(wave * 16 + 64) * 32];
    ushort* dBh0 = &lds[2][(wave * 16) * 32];
    ushort* dBh1 = &lds[2][(wave * 16 + 64) * 32];
    ushort* dBl0 = &lds[3][(wave * 16) * 32];
    ushort* dBl1 = &lds[3][(wave * 16 + 64) * 32];

    const int lr = lane & 15, kb = lane >> 4;
    int aoffB[4], boffB[4];
#pragma unroll
    for (int f = 0; f < 4; ++f) {
        int ra = (wave >> 1) * 64 + f * 16 + lr;
        aoffB[f] = ra * 64 + ((kb ^ ((ra >> 1) & 3)) * 16);
        int rb = (wave & 1) * 64 + f * 16 + lr;
        boffB[f] = rb * 64 + ((kb ^ ((rb >> 1) & 3)) * 16);
    }
    const char* base = (const char*)&lds[0][0];  // tiles at +0, +8192, +16384, +24576

    f32x4 acc[4][4];
#pragma unroll
    for (int i = 0; i < 4; ++i)
#pragma unroll
        for (int j = 0; j < 4; ++j) acc[i][j] = (f32x4)0.f;

    for (int ks = 0; ks < DIM / 32; ++ks) {
        gll16(sAh0, dAh0); gll16(sAh1, dAh1);
        gll16(sAl0, dAl0); gll16(sAl1, dAl1);
        gll16(sBh0, dBh0); gll16(sBh1, dBh1);
        gll16(sBl0, dBl0); gll16(sBl1, dBl1);
        sAh0 += 32; sAh1 += 32; sAl0 += 32; sAl1 += 32;
        sBh0 += 32; sBh1 += 32; sBl0 += 32; sBl1 += 32;
        __syncthreads();   // drains vmcnt: staged data visible

        short8v ah[4], al[4], bh[4], bl[4];
#pragma unroll
        for (int f = 0; f < 4; ++f) {
            ah[f] = *(const short8v*)(base +         aoffB[f]);
            al[f] = *(const short8v*)(base +  8192 + aoffB[f]);
            bh[f] = *(const short8v*)(base + 16384 + boffB[f]);
            bl[f] = *(const short8v*)(base + 24576 + boffB[f]);
        }
#pragma unroll
        for (int i = 0; i < 4; ++i)
#pragma unroll
            for (int j = 0; j < 4; ++j) {
                acc[i][j] = __builtin_amdgcn_mfma_f32_16x16x32_bf16(ah[i], bh[j], acc[i][j], 0, 0, 0);
                acc[i][j] = __builtin_amdgcn_mfma_f32_16x16x32_bf16(ah[i], bl[j], acc[i][j], 0, 0, 0);
                acc[i][j] = __builtin_amdgcn_mfma_f32_16x16x32_bf16(al[i], bh[j], acc[i][j], 0, 0, 0);
            }
        __syncthreads();   // protect LDS from next iteration's staging
    }

    // ---- epilogue: C/D layout col = lane&15, row = (lane>>4)*4 + reg ----
    const int colB = col0 + (wave & 1) * 64 + lr;
    const int rowB = row0 + (wave >> 1) * 64 + kb * 4;
    float bv[4];
#pragma unroll
    for (int j = 0; j < 4; ++j) bv[j] = bias[colB + j * 16];
#pragma unroll
    for (int i = 0; i < 4; ++i) {
#pragma unroll
        for (int j = 0; j < 4; ++j) {
            int cg = colB + j * 16;
#pragma unroll
            for (int rg = 0; rg < 4; ++rg) {
                int rr = rowB + i * 16 + rg;
                if (rr < M) {
                    float o = leaky(acc[i][j][rg] + bv[j]);
                    if (OUTBF) {
                        unsigned hh = f2bf(o);
                        Ch[(size_t)rr * DIM + cg] = (ushort)hh;
                        Cl[(size_t)rr * DIM + cg] = (ushort)f2bf(o - bf2f(hh));
                    } else {
                        Cf[(size_t)rr * DIM + cg] = o;
                    }
                }
            }
        }
    }
}

// ------- NodeNorm (in place) + per-block BatchNorm partial stats -------
__global__ __launch_bounds__(256) void nodenorm_k(
    float* __restrict__ z, float* __restrict__ partials)
{
    __shared__ float part[1024];
    for (int t = threadIdx.x; t < 1024; t += 256) part[t] = 0.f;
    __syncthreads();

    int wave = blockIdx.x * 4 + (threadIdx.x >> 6);
    int lane = threadIdx.x & 63;
    int nw = gridDim.x * 4;
    int per = (N_NODES + nw - 1) / nw;
    int r0 = wave * per;
    int r1 = min(N_NODES, r0 + per);

    float cs[8] = {0, 0, 0, 0, 0, 0, 0, 0};
    float cq[8] = {0, 0, 0, 0, 0, 0, 0, 0};

    for (int r = r0; r < r1; ++r) {
        float* p = z + (size_t)r * DIM;
        float4 a = *(const float4*)(p + lane * 4);
        float4 b = *(const float4*)(p + 256 + lane * 4);
        float s = a.x + a.y + a.z + a.w + b.x + b.y + b.z + b.w;
        float q = a.x * a.x + a.y * a.y + a.z * a.z + a.w * a.w
                + b.x * b.x + b.y * b.y + b.z * b.z + b.w * b.w;
#pragma unroll
        for (int off = 32; off; off >>= 1) {
            s += __shfl_xor(s, off);
            q += __shfl_xor(q, off);
        }
        float mean = s * (1.f / DIM);
        float var = q * (1.f / DIM) - mean * mean;
        float rs = rsqrtf(var + EPS_F);
        a.x = (a.x - mean) * rs; a.y = (a.y - mean) * rs;
        a.z = (a.z - mean) * rs; a.w = (a.w - mean) * rs;
        b.x = (b.x - mean) * rs; b.y = (b.y - mean) * rs;
        b.z = (b.z - mean) * rs; b.w = (b.w - mean) * rs;
        *(float4*)(p + lane * 4) = a;
        *(float4*)(p + 256 + lane * 4) = b;
        cs[0] += a.x; cs[1] += a.y; cs[2] += a.z; cs[3] += a.w;
        cs[4] += b.x; cs[5] += b.y; cs[6] += b.z; cs[7] += b.w;
        cq[0] += a.x * a.x; cq[1] += a.y * a.y; cq[2] += a.z * a.z; cq[3] += a.w * a.w;
        cq[4] += b.x * b.x; cq[5] += b.y * b.y; cq[6] += b.z * b.z; cq[7] += b.w * b.w;
    }
#pragma unroll
    for (int i = 0; i < 4; ++i) {
        atomicAdd(&part[lane * 4 + i], cs[i]);
        atomicAdd(&part[256 + lane * 4 + i], cs[4 + i]);
        atomicAdd(&part[512 + lane * 4 + i], cq[i]);
        atomicAdd(&part[768 + lane * 4 + i], cq[4 + i]);
    }
    __syncthreads();
    float* dst = partials + (size_t)blockIdx.x * 1024;
    *(float4*)(dst + threadIdx.x * 4) = *(const float4*)&part[threadIdx.x * 4];
}

// ------- BatchNorm finalize: scale/shift per column -------
__global__ void bn_finalize_k(
    const float* __restrict__ partials, int nblocks,
    const float* __restrict__ gamma, const float* __restrict__ beta,
    float* __restrict__ sc, float* __restrict__ sh)
{
    int c = blockIdx.x * blockDim.x + threadIdx.x;
    if (c >= DIM) return;
    float s = 0.f, q = 0.f;
#pragma unroll 8
    for (int b = 0; b < nblocks; ++b) {
        s += partials[(size_t)b * 1024 + c];
        q += partials[(size_t)b * 1024 + 512 + c];
    }
    float mean = s * (1.f / N_NODES);
    float var = q * (1.f / N_NODES) - mean * mean;
    float sf = gamma[c] * rsqrtf(var + EPS_F);
    sc[c] = sf;
    sh[c] = beta[c] - mean * sf;
}

// ------- BatchNorm apply + x_local write + sorted-segment pooling -------
__global__ __launch_bounds__(256) void apply_pool_k(
    const float* __restrict__ z, const float* __restrict__ sc, const float* __restrict__ sh,
    const int* __restrict__ batch,
    float* __restrict__ xloc, float* __restrict__ xglob)
{
    int wave = blockIdx.x * 4 + (threadIdx.x >> 6);
    int lane = threadIdx.x & 63;
    int nw = gridDim.x * 4;
    int per = (N_NODES + nw - 1) / nw;
    int r0 = wave * per;
    int r1 = min(N_NODES, r0 + per);
    if (r0 >= r1) return;

    float4 s0 = *(const float4*)(sc + lane * 4);
    float4 s1 = *(const float4*)(sc + 256 + lane * 4);
    float4 t0 = *(const float4*)(sh + lane * 4);
    float4 t1 = *(const float4*)(sh + 256 + lane * 4);

    float pa[8] = {0, 0, 0, 0, 0, 0, 0, 0};
    int curg = batch[r0];
    const int LD = N_LAYERS * DIM;

    for (int r = r0; r < r1; ++r) {
        int g = batch[r];
        if (g != curg) {
#pragma unroll
            for (int i = 0; i < 4; ++i) {
                atomicAdd(xglob + (size_t)curg * LD + lane * 4 + i, pa[i]);
                atomicAdd(xglob + (size_t)curg * LD + 256 + lane * 4 + i, pa[4 + i]);
                pa[i] = 0.f; pa[4 + i] = 0.f;
            }
            curg = g;
        }
        const float* p = z + (size_t)r * DIM;
        float4 a = *(const float4*)(p + lane * 4);
        float4 b = *(const float4*)(p + 256 + lane * 4);
        a.x = fmaf(a.x, s0.x, t0.x); a.y = fmaf(a.y, s0.y, t0.y);
        a.z = fmaf(a.z, s0.z, t0.z); a.w = fmaf(a.w, s0.w, t0.w);
        b.x = fmaf(b.x, s1.x, t1.x); b.y = fmaf(b.y, s1.y, t1.y);
        b.z = fmaf(b.z, s1.z, t1.z); b.w = fmaf(b.w, s1.w, t1.w);
        *(float4*)(xloc + (size_t)r * LD + lane * 4) = a;
        *(float4*)(xloc + (size_t)r * LD + 256 + lane * 4) = b;
        pa[0] += a.x; pa[1] += a.y; pa[2] += a.z; pa[3] += a.w;
        pa[4] += b.x; pa[5] += b.y; pa[6] += b.z; pa[7] += b.w;
    }
#pragma unroll
    for (int i = 0; i < 4; ++i) {
        atomicAdd(xglob + (size_t)curg * LD + lane * 4 + i, pa[i]);
        atomicAdd(xglob + (size_t)curg * LD + 256 + lane * 4 + i, pa[4 + i]);
    }
}

extern "C" void kernel_launch(void* const* d_in, const int* in_sizes, int n_in,
                              void* d_out, int out_size, void* d_ws, size_t ws_size,
                              hipStream_t stream)
{
    const float* x     = (const float*)d_in[0];
    const int*   ei    = (const int*)d_in[1];
    const int*   batch = (const int*)d_in[2];
    const float* W1    = (const float*)d_in[3];
    const float* b1    = (const float*)d_in[4];
    const float* W2    = (const float*)d_in[5];
    const float* b2    = (const float*)d_in[6];
    const float* gamma = (const float*)d_in[7];
    const float* beta  = (const float*)d_in[8];

    float* out = (float*)d_out;
    const size_t XG = (size_t)N_GRAPHS * N_LAYERS * DIM;
    float* xglob_base = out;
    float* xloc_base  = out + XG;

    const size_t PAIR_ELEMS = (size_t)MP * DIM;   // ushorts per hi or lo matrix
    char* w = (char*)d_ws;
    ushort* Ah0 = (ushort*)w;
    ushort* Al0 = Ah0 + PAIR_ELEMS;
    float*  fbuf = (float*)w;                     // aliases Ah0/Al0 — lifetimes disjoint
    w += PAIR_ELEMS * 2 * sizeof(ushort);
    ushort* Ah1 = (ushort*)w;
    ushort* Al1 = Ah1 + PAIR_ELEMS;
    w += PAIR_ELEMS * 2 * sizeof(ushort);
    ushort* Wh = (ushort*)w; w += (size_t)2 * N_LAYERS * DIM * DIM * sizeof(ushort);
    ushort* Wl = (ushort*)w; w += (size_t)2 * N_LAYERS * DIM * DIM * sizeof(ushort);
    const int NN_BLOCKS = 256;
    float* partials = (float*)w; w += (size_t)NN_BLOCKS * 1024 * sizeof(float);
    float* sc = (float*)w; w += DIM * sizeof(float);
    float* sh = (float*)w; w += DIM * sizeof(float);
    int* deg    = (int*)w; w += (size_t)N_NODES * sizeof(int);
    int* off    = (int*)w; w += (size_t)(N_NODES + 1) * sizeof(int);
    int* cursor = (int*)w; w += (size_t)N_NODES * sizeof(int);
    int* csr    = (int*)w;

    hipMemsetAsync(xglob_base, 0, XG * sizeof(float), stream);
    hipMemsetAsync(deg, 0, N_NODES * sizeof(int), stream);

    // CSR build + weight prep (once per launch)
    hist_k<<<(N_EDGES + 255) / 256, 256, 0, stream>>>(ei, deg);
    scan_k<<<1, 1024, 0, stream>>>(deg, off, cursor);
    fill_k<<<(N_EDGES + 255) / 256, 256, 0, stream>>>(ei, cursor, csr);
    wprep_k<<<dim3(16, 16, 2 * N_LAYERS), dim3(32, 8), 0, stream>>>(W1, W2, Wh, Wl);

    for (int i = 0; i < N_LAYERS; ++i) {
        const float* h;
        int hstride;
        if (i == 0) { h = x; hstride = DIM; }
        else        { h = xloc_base + (size_t)(i - 1) * DIM; hstride = N_LAYERS * DIM; }

        aggregate_k<<<(N_NODES + 3) / 4, 256, 0, stream>>>(off, csr, h, hstride, Ah0, Al0);

        // GEMM1: z1 = leaky(z @ W1 + b1), output as bf16 hi/lo pair
        gemm_mfma_k<1><<<dim3(DIM / 128, (MP / 128)), 256, 0, stream>>>(
            Ah0, Al0,
            Wh + (size_t)i * DIM * DIM, Wl + (size_t)i * DIM * DIM,
            b1 + (size_t)i * DIM, nullptr, Ah1, Al1, N_NODES);

        // GEMM2: z2 = leaky(z1 @ W2 + b2), fp32 output for normalization
        gemm_mfma_k<0><<<dim3(DIM / 128, (MP / 128)), 256, 0, stream>>>(
            Ah1, Al1,
            Wh + (size_t)(N_LAYERS + i) * DIM * DIM, Wl + (size_t)(N_LAYERS + i) * DIM * DIM,
            b2 + (size_t)i * DIM, fbuf, nullptr, nullptr, N_NODES);

        nodenorm_k<<<NN_BLOCKS, 256, 0, stream>>>(fbuf, partials);

        bn_finalize_k<<<2, 256, 0, stream>>>(partials, NN_BLOCKS,
            gamma + (size_t)i * DIM, beta + (size_t)i * DIM, sc, sh);

        apply_pool_k<<<512, 256, 0, stream>>>(fbuf, sc, sh, batch,
            xloc_base + (size_t)i * DIM, xglob_base + (size_t)i * DIM);
    }
}